// Round 1
// baseline (173.238 us; speedup 1.0000x reference)
//
#include <hip/hip_runtime.h>
#include <hip/hip_cooperative_groups.h>

namespace cg = cooperative_groups;

#define NB 4
#define LB 512
#define DB 1024
#define PB 768
#define NBINS 64
#define LEN_KEEP 128          // int(512 * (1 - 0.75))
#define EPSL 1e-19f
#define WIN 3                 // excluded buckets >=3.5 spacings: kern <= 2e-7,
                              // dropped mass ~1e-5 vs per-bin sums O(10)
#define NBLK 512
#define NTHR 256

#if defined(__has_builtin)
#if __has_builtin(__builtin_amdgcn_exp2f)
#define HAVE_EXP2 1
#endif
#endif

__device__ __forceinline__ float fast_exp2(float x) {
#ifdef HAVE_EXP2
    return __builtin_amdgcn_exp2f(x);   // raw v_exp_f32
#else
    return __expf(x * 0.69314718055994530942f);
#endif
}

// ---------------------------------------------------------------------------
// Single cooperative kernel, 512 blocks x 256 threads (2 blocks/CU, 8 waves/CU).
// Theory: previous 3-launch version (76.5us) moved only ~17MB (roofline ~3us);
// all top-5 rocprof dispatches were harness fills => per-launch overhead +
// inter-kernel gaps dominate. Fuse with 2 grid.sync()'s.
//   Phase A: grid-stride min/max partials (512 per-block partials to ws).
//   Phase B: entropy, ONE WAVE PER TOKEN. Wave-private LDS region =>
//            no __syncthreads at all; wave-internal s_waitcnt lgkmcnt(0)
//            orders LDS atomics. Bucket scan via __shfl_up; window bounds
//            via __shfl (bs[] eliminated).
//   Phase C: rank+gather, 4 elements/block, one wave per element.
//            Rank reads interleaved j = lane + 64k => stride-1 across lanes,
//            bank-conflict-free (old slice*32+k layout was 16-way).
// ---------------------------------------------------------------------------
__global__ __launch_bounds__(NTHR, 2) void fused_kernel(
        const float* __restrict__ x, const float* __restrict__ img,
        float* __restrict__ out_x, float* __restrict__ out_mask,
        float* __restrict__ out_rest,
        float* __restrict__ bminp, float* __restrict__ bmaxp,
        float* __restrict__ ent)
{
    __shared__ float lds[4 * 896];   // per-wave: snv[768] | cnt[64] | pos[64]
    __shared__ float shred[8];       // phase A cross-wave reduce
    __shared__ int keep_list[16];    // phase C: (slot<<16)|row
    __shared__ int nkeep;

    const int tid = threadIdx.x;
    const int bid = blockIdx.x;
    const int lane = tid & 63;
    const int w = tid >> 6;

    // ---------------- Phase A: min/max partials over img ----------------
    {
        const float4* v4 = (const float4*)img;     // 393216 float4 total
        int g = bid * NTHR + tid;                  // 131072 threads x 3
        float mn = 1e30f, mx = -1e30f;
#pragma unroll
        for (int k = 0; k < 3; ++k) {
            float4 t4 = v4[g + k * (NBLK * NTHR)];
            mn = fminf(mn, fminf(fminf(t4.x, t4.y), fminf(t4.z, t4.w)));
            mx = fmaxf(mx, fmaxf(fmaxf(t4.x, t4.y), fmaxf(t4.z, t4.w)));
        }
        for (int m = 1; m < 64; m <<= 1) {
            mn = fminf(mn, __shfl_xor(mn, m, 64));
            mx = fmaxf(mx, __shfl_xor(mx, m, 64));
        }
        if (lane == 0) { shred[w] = mn; shred[4 + w] = mx; }
        __syncthreads();
        if (tid == 0) {
            bminp[bid] = fminf(fminf(shred[0], shred[1]), fminf(shred[2], shred[3]));
            bmaxp[bid] = fmaxf(fmaxf(shred[4], shred[5]), fmaxf(shred[6], shred[7]));
        }
    }
    cg::this_grid().sync();

    // ---------------- Phase B: windowed KDE entropy, wave-per-token -------
    {
        // every wave redundantly reduces the 512 partials (L2 broadcast, cheap)
        float mn = 1e30f, mx = -1e30f;
#pragma unroll
        for (int k = 0; k < 8; ++k) {
            mn = fminf(mn, bminp[lane + 64 * k]);
            mx = fmaxf(mx, bmaxp[lane + 64 * k]);
        }
        for (int m = 1; m < 64; m <<= 1) {
            mn = fminf(mn, __shfl_xor(mn, m, 64));
            mx = fmaxf(mx, __shfl_xor(mx, m, 64));
        }
        const float vmin = mn;
        const float inv = 1.0f / (mx - mn);

        const int t = bid * 4 + w;                 // token 0..2047
        float* snv = lds + w * 896;                // wave-private region
        int*   cnt = (int*)(snv + 768);
        int*   pos = (int*)(snv + 832);

        cnt[lane] = 0;
        asm volatile("s_waitcnt lgkmcnt(0)" ::: "memory");

        // load 12 values/lane (3x float4, coalesced), normalize, histogram
        const float4* row4 = (const float4*)(img + (size_t)t * PB);
        float4 a = row4[lane], b = row4[lane + 64], c = row4[lane + 128];
        float nv[12] = { a.x, a.y, a.z, a.w, b.x, b.y, b.z, b.w,
                         c.x, c.y, c.z, c.w };
        int mb[12];
#pragma unroll
        for (int k = 0; k < 12; ++k) {
            nv[k] = (nv[k] - vmin) * inv;
            mb[k] = min(63, max(0, __float2int_rn(nv[k] * 63.0f)));
            atomicAdd(&cnt[mb[k]], 1);
        }
        asm volatile("s_waitcnt lgkmcnt(0)" ::: "memory");

        // exclusive scan in-wave; window bounds straight from the scan regs
        int c0 = cnt[lane];
        int incl = c0;
        for (int off = 1; off < 64; off <<= 1) {
            int up = __shfl_up(incl, off, 64);
            if (lane >= off) incl += up;
        }
        pos[lane] = incl - c0;                     // exclusive prefix cursor
        int lov = __shfl(incl, max(lane - (WIN + 1), 0), 64);
        int lo = (lane >= WIN + 1) ? lov : 0;      // bs[max(0,lane-WIN)]
        int hi = __shfl(incl, min(lane + WIN, 63), 64); // bs[min(64,lane+WIN+1)]
        asm volatile("s_waitcnt lgkmcnt(0)" ::: "memory");

        // scatter into bucket-sorted order
#pragma unroll
        for (int k = 0; k < 12; ++k) {
            snv[atomicAdd(&pos[mb[k]], 1)] = nv[k];
        }
        asm volatile("s_waitcnt lgkmcnt(0)" ::: "memory");

        // windowed accumulation: lane = bin, full window in this wave
        const float bv = (float)lane * (1.0f / 63.0f);
        const float negC = -7213.4755859375f;      // -(5000 * log2 e)
        float acc = 0.0f;
        for (int j = lo; j < hi; ++j) {
            float d = snv[j] - bv;
            acc += fast_exp2(d * d * negC);
        }

        // pdf normalize + entropy, all in-wave
        float pdf = acc * (1.0f / (float)PB);
        float s = pdf;
        for (int m = 1; m < 64; m <<= 1) s += __shfl_xor(s, m, 64);
        float p = pdf / (s + EPSL) + EPSL;
        float term = p * __logf(p);
        for (int m = 1; m < 64; m <<= 1) term += __shfl_xor(term, m, 64);
        if (lane == 0) ent[t] = -term;
    }
    cg::this_grid().sync();

    // ---------------- Phase C: stable rank + self-owned gather ------------
    {
        const int n = bid >> 7;                    // row 0..3
        const int ibase = (bid & 127) * 4;         // 4 elements per block
        float* sh = lds;                           // ent row (512 floats)
        if (tid == 0) nkeep = 0;
        sh[tid]       = ent[n * LB + tid];
        sh[256 + tid] = ent[n * LB + 256 + tid];
        __syncthreads();

        const int i = ibase + w;                   // this wave's element
        unsigned long long ci =
            ((unsigned long long)__float_as_uint(sh[i]) << 32) | (unsigned)i;
        int r = 0;
#pragma unroll
        for (int k = 0; k < 8; ++k) {              // j = lane + 64k: stride-1
            int j = lane + 64 * k;                 // across lanes, 0 conflicts
            unsigned long long cj =
                ((unsigned long long)__float_as_uint(sh[j]) << 32) | (unsigned)j;
            r += (cj < ci) ? 1 : 0;
        }
        for (int m = 1; m < 64; m <<= 1) r += __shfl_xor(r, m, 64);
        if (lane == 0) {
            out_rest[n * LB + i] = (float)r;
            out_mask[n * LB + i] = (r < LEN_KEEP) ? 0.0f : 1.0f;
            if (r < LEN_KEEP) {
                int e = atomicAdd(&nkeep, 1);
                keep_list[e] = (r << 16) | i;
            }
        }
        __syncthreads();

        const int nk = nkeep;                      // avg 1, max 4 per block
        for (int e = 0; e < nk; ++e) {
            int slot = keep_list[e] >> 16;
            int rowi = keep_list[e] & 0xFFFF;
            const float4* src = (const float4*)(x + ((size_t)(n * LB + rowi)) * DB);
            float4* dst = (float4*)(out_x + ((size_t)(n * LEN_KEEP + slot)) * DB);
            dst[tid] = src[tid];                   // 256 x 16B = full 4KB row
        }
    }
}

extern "C" void kernel_launch(void* const* d_in, const int* in_sizes, int n_in,
                              void* d_out, int out_size, void* d_ws, size_t ws_size,
                              hipStream_t stream) {
    const float* x   = (const float*)d_in[0];   // (4,512,1024)
    const float* img = (const float*)d_in[1];   // (4,512,768)

    float* out      = (float*)d_out;
    float* out_x    = out;                               // 4*128*1024
    float* out_mask = out + (size_t)NB * LEN_KEEP * DB;  // 4*512
    float* out_rest = out_mask + NB * LB;                // 4*512

    float* ws    = (float*)d_ws;
    float* bminp = ws;            // 512
    float* bmaxp = ws + 512;      // 512
    float* ent   = ws + 1024;     // 2048

    void* args[] = { (void*)&x, (void*)&img, (void*)&out_x, (void*)&out_mask,
                     (void*)&out_rest, (void*)&bminp, (void*)&bmaxp, (void*)&ent };
    hipLaunchCooperativeKernel((const void*)fused_kernel, dim3(NBLK), dim3(NTHR),
                               args, 0, stream);
}

// Round 2
// 76.255 us; speedup vs baseline: 2.2718x; 2.2718x over previous
//
#include <hip/hip_runtime.h>

#define NB 4
#define LB 512
#define DB 1024
#define PB 768
#define NBINS 64
#define LEN_KEEP 128          // int(512 * (1 - 0.75))
#define EPSL 1e-19f
#define WIN 3                 // excluded buckets >=3.5 spacings: kern <= 2e-7,
                              // dropped mass ~1e-5 vs per-bin sums O(10)

#if defined(__has_builtin)
#if __has_builtin(__builtin_amdgcn_exp2f)
#define HAVE_EXP2 1
#endif
#endif

__device__ __forceinline__ float fast_exp2(float x) {
#ifdef HAVE_EXP2
    return __builtin_amdgcn_exp2f(x);   // raw v_exp_f32
#else
    return __expf(x * 0.69314718055994530942f);
#endif
}

// ---------------------------------------------------------------------------
// Lesson R1: cooperative grid.sync cost ~40us each on a 512-block grid
// (fused kernel: 97us device, VALU 4.4%, HBM 1.2% => idle spin). Kernel
// boundaries ARE the cheap global barrier (~2-3us each under graph capture).
// Back to 3 launches; keep the phase-internal wins validated inside the
// fused kernel (wave-per-token entropy, conflict-free rank).
// ---------------------------------------------------------------------------

// K1: min/max partials. 256 blocks x 256 threads, 6 float4 each (full CU
// coverage; old 64-block version left 75% of CUs idle).
__global__ __launch_bounds__(256) void minmax_partial(
        const float4* __restrict__ v,
        float* __restrict__ bmin, float* __restrict__ bmax) {
    __shared__ float shred[8];
    int tid = threadIdx.x;
    int lane = tid & 63, w = tid >> 6;
    int base = blockIdx.x * 256 + tid;
    float mn = 1e30f, mx = -1e30f;
#pragma unroll
    for (int k = 0; k < 6; ++k) {      // 256*256*6 = 393216 float4 = 1.57M floats
        float4 t4 = v[base + k * 65536];
        mn = fminf(mn, fminf(fminf(t4.x, t4.y), fminf(t4.z, t4.w)));
        mx = fmaxf(mx, fmaxf(fmaxf(t4.x, t4.y), fmaxf(t4.z, t4.w)));
    }
    for (int m = 1; m < 64; m <<= 1) {
        mn = fminf(mn, __shfl_xor(mn, m, 64));
        mx = fmaxf(mx, __shfl_xor(mx, m, 64));
    }
    if (lane == 0) { shred[w] = mn; shred[4 + w] = mx; }
    __syncthreads();
    if (tid == 0) {
        bmin[blockIdx.x] = fminf(fminf(shred[0], shred[1]), fminf(shred[2], shred[3]));
        bmax[blockIdx.x] = fmaxf(fmaxf(shred[4], shred[5]), fmaxf(shred[6], shred[7]));
    }
}

// ---------------------------------------------------------------------------
// K2: windowed KDE entropy, ONE WAVE PER TOKEN (512 blocks x 4 waves).
//   Wave-private LDS region => ZERO __syncthreads (old version had 5).
//   All cross-lane combining via shuffles; LDS atomics ordered by
//   wave-internal s_waitcnt lgkmcnt(0). float4 row loads (old: 3 scalar).
//   Counting-sort into 64 buckets, then lane b sums exp2(-7213.476*d^2)
//   over buckets [b-WIN, b+WIN] (~84 values, bounds from the scan regs).
// ---------------------------------------------------------------------------
__global__ __launch_bounds__(256) void entropy_kernel(
        const float* __restrict__ img,
        const float* __restrict__ bminp, const float* __restrict__ bmaxp,
        float* __restrict__ ent) {
    __shared__ float lds[4 * 896];   // per-wave: snv[768] | cnt[64] | pos[64]
    const int tid = threadIdx.x;
    const int lane = tid & 63;
    const int w = tid >> 6;

    // every wave redundantly reduces the 256 partials (L2 broadcast, no barrier)
    float mn = 1e30f, mx = -1e30f;
#pragma unroll
    for (int k = 0; k < 4; ++k) {
        mn = fminf(mn, bminp[lane + 64 * k]);
        mx = fmaxf(mx, bmaxp[lane + 64 * k]);
    }
    for (int m = 1; m < 64; m <<= 1) {
        mn = fminf(mn, __shfl_xor(mn, m, 64));
        mx = fmaxf(mx, __shfl_xor(mx, m, 64));
    }
    const float vmin = mn;
    const float inv = 1.0f / (mx - mn);

    const int t = blockIdx.x * 4 + w;              // token 0..2047
    float* snv = lds + w * 896;                    // wave-private region
    int*   cnt = (int*)(snv + 768);
    int*   pos = (int*)(snv + 832);

    cnt[lane] = 0;
    asm volatile("s_waitcnt lgkmcnt(0)" ::: "memory");

    // 12 values/lane (3x float4, coalesced), normalize, histogram
    const float4* row4 = (const float4*)(img + (size_t)t * PB);
    float4 a = row4[lane], b = row4[lane + 64], c = row4[lane + 128];
    float nv[12] = { a.x, a.y, a.z, a.w, b.x, b.y, b.z, b.w,
                     c.x, c.y, c.z, c.w };
    int mb[12];
#pragma unroll
    for (int k = 0; k < 12; ++k) {
        nv[k] = (nv[k] - vmin) * inv;
        mb[k] = min(63, max(0, __float2int_rn(nv[k] * 63.0f)));
        atomicAdd(&cnt[mb[k]], 1);
    }
    asm volatile("s_waitcnt lgkmcnt(0)" ::: "memory");

    // exclusive scan in-wave; window bounds straight from the scan regs
    int c0 = cnt[lane];
    int incl = c0;
    for (int off = 1; off < 64; off <<= 1) {
        int up = __shfl_up(incl, off, 64);
        if (lane >= off) incl += up;
    }
    pos[lane] = incl - c0;                         // exclusive prefix cursor
    int lov = __shfl(incl, max(lane - (WIN + 1), 0), 64);
    int lo = (lane >= WIN + 1) ? lov : 0;          // bs[max(0,lane-WIN)]
    int hi = __shfl(incl, min(lane + WIN, 63), 64);// bs[min(64,lane+WIN+1)]
    asm volatile("s_waitcnt lgkmcnt(0)" ::: "memory");

    // scatter into bucket-sorted order
#pragma unroll
    for (int k = 0; k < 12; ++k) {
        snv[atomicAdd(&pos[mb[k]], 1)] = nv[k];
    }
    asm volatile("s_waitcnt lgkmcnt(0)" ::: "memory");

    // windowed accumulation: lane = bin
    const float bv = (float)lane * (1.0f / 63.0f);
    const float negC = -7213.4755859375f;          // -(5000 * log2 e)
    float acc = 0.0f;
    for (int j = lo; j < hi; ++j) {
        float d = snv[j] - bv;
        acc += fast_exp2(d * d * negC);
    }

    // pdf normalize + entropy, all in-wave
    float pdf = acc * (1.0f / (float)PB);
    float s = pdf;
    for (int m = 1; m < 64; m <<= 1) s += __shfl_xor(s, m, 64);
    float p = pdf / (s + EPSL) + EPSL;
    float term = p * __logf(p);
    for (int m = 1; m < 64; m <<= 1) term += __shfl_xor(term, m, 64);
    if (lane == 0) ent[t] = -term;
}

// ---------------------------------------------------------------------------
// K3: stable rank + self-owned gather. 512 blocks x 256 threads (full CU
//   coverage; old 128-block version used half the CUs). One WAVE per element:
//   rank reads j = lane + 64k => stride-1 across lanes, bank-conflict-free
//   (old slice*32+k layout was 16-way conflicted). Each block gathers only
//   the x rows it ranked kept (avg 1, max 4).
// ---------------------------------------------------------------------------
__global__ __launch_bounds__(256) void rank_gather_kernel(
        const float* __restrict__ x, const float* __restrict__ ent,
        float* __restrict__ out_x, float* __restrict__ out_mask,
        float* __restrict__ out_rest) {
    __shared__ float sh[LB];
    __shared__ int keep_list[8];     // (slot<<16) | row ; max 4 per block
    __shared__ int nkeep;
    const int bid = blockIdx.x, tid = threadIdx.x;
    const int lane = tid & 63, w = tid >> 6;
    const int n = bid >> 7;                   // row 0..3
    const int i = (bid & 127) * 4 + w;        // this wave's element

    if (tid == 0) nkeep = 0;
    sh[tid]       = ent[n * LB + tid];
    sh[256 + tid] = ent[n * LB + 256 + tid];
    __syncthreads();

    unsigned long long ci =
        ((unsigned long long)__float_as_uint(sh[i]) << 32) | (unsigned)i;
    int r = 0;
#pragma unroll
    for (int k = 0; k < 8; ++k) {             // stride-1 across lanes: 0 conflicts
        int j = lane + 64 * k;
        unsigned long long cj =
            ((unsigned long long)__float_as_uint(sh[j]) << 32) | (unsigned)j;
        r += (cj < ci) ? 1 : 0;
    }
    for (int m = 1; m < 64; m <<= 1) r += __shfl_xor(r, m, 64);
    if (lane == 0) {
        out_rest[n * LB + i] = (float)r;
        out_mask[n * LB + i] = (r < LEN_KEEP) ? 0.0f : 1.0f;
        if (r < LEN_KEEP) {
            int e = atomicAdd(&nkeep, 1);
            keep_list[e] = (r << 16) | i;
        }
    }
    __syncthreads();

    const int nk = nkeep;                     // avg 1, max 4
    for (int e = 0; e < nk; ++e) {
        int slot = keep_list[e] >> 16;
        int rowi = keep_list[e] & 0xFFFF;
        const float4* src = (const float4*)(x + ((size_t)(n * LB + rowi)) * DB);
        float4* dst = (float4*)(out_x + ((size_t)(n * LEN_KEEP + slot)) * DB);
        dst[tid] = src[tid];                  // 256 threads x 16B = full 4KB row
    }
}

extern "C" void kernel_launch(void* const* d_in, const int* in_sizes, int n_in,
                              void* d_out, int out_size, void* d_ws, size_t ws_size,
                              hipStream_t stream) {
    const float* x   = (const float*)d_in[0];   // (4,512,1024)
    const float* img = (const float*)d_in[1];   // (4,512,768)

    float* out      = (float*)d_out;
    float* out_x    = out;                               // 4*128*1024
    float* out_mask = out + (size_t)NB * LEN_KEEP * DB;  // 4*512
    float* out_rest = out_mask + NB * LB;                // 4*512

    float* ws    = (float*)d_ws;
    float* bminp = ws;            // 256
    float* bmaxp = ws + 256;      // 256
    float* ent   = ws + 512;      // 2048

    minmax_partial<<<256, 256, 0, stream>>>((const float4*)img, bminp, bmaxp);
    entropy_kernel<<<NB * LB / 4, 256, 0, stream>>>(img, bminp, bmaxp, ent);
    rank_gather_kernel<<<NB * LB / 4, 256, 0, stream>>>(x, ent, out_x, out_mask, out_rest);
}